// Round 10
// baseline (629.363 us; speedup 1.0000x reference)
//
#include <hip/hip_runtime.h>
#include <stdint.h>

#define BB 16
#define SS 2048
#define FF 512
#define DD 128
#define CC 1000

typedef __attribute__((ext_vector_type(8))) short bf16x8;
typedef __attribute__((ext_vector_type(4))) float f32x4;

__device__ __forceinline__ unsigned short f2bf(float f) {
  unsigned x;
  __builtin_memcpy(&x, &f, 4);
  x = x + 0x7FFFu + ((x >> 16) & 1u);
  return (unsigned short)(x >> 16);
}
__device__ __forceinline__ float bf2f(unsigned short u) {
  unsigned x = ((unsigned)u) << 16;
  float f;
  __builtin_memcpy(&f, &x, 4);
  return f;
}
__device__ __forceinline__ unsigned pk2(float a, float b) {
  return (unsigned)f2bf(a) | ((unsigned)f2bf(b) << 16);
}

// ---- workspace layout (bytes) ----
#define WS_PK   0          // packed mask bits uint32 [B][S][64] (8 MB)
#define WS_Q    8388608    // bf16 [B][S][128], q pre-scaled by D^-0.5
#define WS_K    16777216
#define WS_V    25165824
#define WS_WT   33554432   // bf16 WT[3][128][512]
#define WS_WGP  33947648   // float wgp[B][128 rowgroups][2048] partial colsums (16 MB)
#define WS_END  50724864

// ---------------- prep: mask probe (per-block) + mask pack + W transpose ----------------
__global__ __launch_bounds__(256) void k_prep(const void* __restrict__ mask,
                                              const float* __restrict__ Wq,
                                              const float* __restrict__ Wk,
                                              const float* __restrict__ Wv,
                                              unsigned short* __restrict__ wt,
                                              unsigned* __restrict__ pk) {
  __shared__ unsigned red;
  const int tid = threadIdx.x;
  if (tid == 0) red = 0;
  __syncthreads();
  {  // probe the global mask head (4 KB): int32 masks never set bits 8..31
    unsigned a = 0;
    const unsigned* m32 = (const unsigned*)mask;
#pragma unroll
    for (int j = 0; j < 4; ++j) a |= m32[tid * 4 + j] & 0xFFFFFF00u;
    if (a) atomicOr(&red, 1u);
  }
  __syncthreads();
  const bool isInt = (red == 0);

  const long long base = (long long)blockIdx.x * 32768;
  for (int it = 0; it < 128; ++it) {
    long long e = base + it * 256 + tid;
    int val;
    if (isInt) val = ((const int*)mask)[e];
    else       val = ((const unsigned char*)mask)[e];
    unsigned long long bal = __ballot(val != 0);
    if ((tid & 31) == 0)
      pk[e >> 5] = (unsigned)((tid & 63) ? (bal >> 32) : bal);
  }

  if (blockIdx.x < 768) {
    int idx = blockIdx.x * 256 + tid;
    int ty = idx >> 16;
    int o = idx & 65535;
    int d = o >> 9, f = o & 511;
    const float* W = ty == 0 ? Wq : (ty == 1 ? Wk : Wv);
    wt[idx] = f2bf(W[f * DD + d]);
  }
}

// ---------------- QKV projection (R4-proven, verbatim) ----------------
__global__ __launch_bounds__(256) void k_proj(const float* __restrict__ xg,
                                              const unsigned short* __restrict__ wtg,
                                              const float* __restrict__ bq,
                                              const float* __restrict__ bk,
                                              const float* __restrict__ bv,
                                              unsigned short* __restrict__ qo,
                                              unsigned short* __restrict__ ko,
                                              unsigned short* __restrict__ vo) {
  __shared__ __align__(16) char lA[8192];
  __shared__ __align__(16) char lB[8192];
  const int tid = threadIdx.x;
  const int lane = tid & 63;
  const int wv = tid >> 6;
  const int colL = lane & 15, quad = lane >> 4;
  const int blk = blockIdx.x, ty = blockIdx.y;
  const float* bias = ty == 0 ? bq : (ty == 1 ? bk : bv);
  unsigned short* outp = ty == 0 ? qo : (ty == 1 ? ko : vo);
  const float scale = ty == 0 ? 0.08838834764831845f : 1.0f;
  const unsigned short* wbase = wtg + (size_t)ty * 65536;
  const int m0 = (wv & 1) * 64, n0 = (wv >> 1) * 64;

  f32x4 acc[4][4];
  const f32x4 z4 = {0.f, 0.f, 0.f, 0.f};
#pragma unroll
  for (int mi = 0; mi < 4; ++mi)
#pragma unroll
    for (int ni = 0; ni < 4; ++ni) acc[mi][ni] = z4;

  for (int ic = 0; ic < 16; ++ic) {
    const int k0 = ic * 32;
    uint4 va[2], vb[2];
#pragma unroll
    for (int rr = 0; rr < 2; ++rr) {
      int p = rr * 256 + tid;
      int row = p >> 2, c = p & 3;
      const float* xp = xg + (size_t)(blk * 128 + row) * FF + k0 + c * 8;
      float4 x0 = *(const float4*)xp;
      float4 x1 = *(const float4*)(xp + 4);
      va[rr].x = pk2(x0.x, x0.y); va[rr].y = pk2(x0.z, x0.w);
      va[rr].z = pk2(x1.x, x1.y); va[rr].w = pk2(x1.z, x1.w);
      vb[rr] = *(const uint4*)(wbase + (size_t)row * FF + k0 + c * 8);
    }
    __syncthreads();
#pragma unroll
    for (int rr = 0; rr < 2; ++rr) {
      int p = rr * 256 + tid;
      int row = p >> 2, c = p & 3;
      int phys = c ^ ((row >> 1) & 3);
      *(uint4*)(lA + row * 64 + phys * 16) = va[rr];
      *(uint4*)(lB + row * 64 + phys * 16) = vb[rr];
    }
    __syncthreads();
    bf16x8 af[4], bfr[4];
#pragma unroll
    for (int mi = 0; mi < 4; ++mi) {
      int ar = m0 + mi * 16 + colL;
      int phys = quad ^ ((ar >> 1) & 3);
      af[mi] = *(const bf16x8*)(lA + ar * 64 + phys * 16);
    }
#pragma unroll
    for (int ni = 0; ni < 4; ++ni) {
      int br = n0 + ni * 16 + colL;
      int phys = quad ^ ((br >> 1) & 3);
      bfr[ni] = *(const bf16x8*)(lB + br * 64 + phys * 16);
    }
#pragma unroll
    for (int mi = 0; mi < 4; ++mi)
#pragma unroll
      for (int ni = 0; ni < 4; ++ni)
        acc[mi][ni] = __builtin_amdgcn_mfma_f32_16x16x32_bf16(af[mi], bfr[ni], acc[mi][ni], 0, 0, 0);
  }
#pragma unroll
  for (int ni = 0; ni < 4; ++ni) {
    int col = n0 + ni * 16 + colL;
    float bval = bias[col];
#pragma unroll
    for (int mi = 0; mi < 4; ++mi) {
#pragma unroll
      for (int r = 0; r < 4; ++r) {
        int row = blk * 128 + m0 + mi * 16 + quad * 4 + r;
        float val = (acc[mi][ni][r] + bval) * scale;
        outp[(size_t)row * DD + col] = f2bf(val);
      }
    }
  }
}

// ---------------- fused attention: 16-row blocks, wave-independent main loop -------------
// Block = (16 q-rows, batch b), 512 thr = 8 waves. Each wave owns 4 t-chunks
// (interleaved: c = wq + 8*it) -> 256 t. K B-fragments direct from global
// (L2-resident; R9-verified address math). P[16][2048] bf16 in LDS (64 KB,
// row-XOR swizzle) -> ~70 KB LDS -> 2 blocks/CU = 4 waves/SIMD. Zero
// main-loop barriers; 2-deep static double-buffered K loads.
__global__ __launch_bounds__(512, 4) void k_fatt(const unsigned short* __restrict__ qg,
                                                 const unsigned short* __restrict__ kg,
                                                 const unsigned* __restrict__ pk,
                                                 float* __restrict__ wgp) {
  __shared__ __align__(16) unsigned short pt[16 * 2048];  // 65536 B
  __shared__ unsigned mk[16 * 65];                        // 4160 B
  __shared__ float zfin[16];
  __shared__ float zinvl[16];

  const int tid = threadIdx.x;
  const int lane = tid & 63, wq = tid >> 6;     // wave owns chunks wq, wq+8, wq+16, wq+24
  const int colL = lane & 15, quad = lane >> 4;
  const int r0 = blockIdx.x * 16;
  const int b = blockIdx.y;

  for (int i = tid; i < 1024; i += 512) {
    int row = i >> 6, w = i & 63;
    mk[row * 65 + w] = pk[((size_t)b * SS + r0 + row) * 64 + w];
  }
  if (tid < 16) zfin[tid] = 0.f;

  // Q A-fragments: all waves share the same 16 rows (m = colL)
  bf16x8 qf[4];
  {
    int qrow = r0 + colL;
    const unsigned short* qp = qg + ((size_t)b * SS + qrow) * DD + quad * 8;
#pragma unroll
    for (int kk = 0; kk < 4; ++kk) qf[kk] = *(const bf16x8*)(qp + kk * 32);
  }
  __syncthreads();   // mk + zfin-zero visible   [barrier 1]

  const int rbase = quad * 4;
  const unsigned short* kgb = kg + (size_t)b * SS * DD + quad * 8;
  float z[4] = {0.f, 0.f, 0.f, 0.f};

  // n-tile i (0..15): chunk c = wq + 8*(i>>2), t = c*64 + (i&3)*16 + colL
  bf16x8 bb[2][4];
  {
    const unsigned short* kp = kgb + (size_t)(wq * 64 + colL) * DD;
#pragma unroll
    for (int kk = 0; kk < 4; ++kk) bb[0][kk] = *(const bf16x8*)(kp + kk * 32);
  }
#pragma unroll
  for (int i = 0; i < 16; ++i) {
    if (i < 15) {
      const int i2 = i + 1;
      const int t2 = (wq + 8 * (i2 >> 2)) * 64 + (i2 & 3) * 16 + colL;
      const unsigned short* kp = kgb + (size_t)t2 * DD;
#pragma unroll
      for (int kk = 0; kk < 4; ++kk) bb[i2 & 1][kk] = *(const bf16x8*)(kp + kk * 32);
    }
    f32x4 acc = {0.f, 0.f, 0.f, 0.f};
    acc = __builtin_amdgcn_mfma_f32_16x16x32_bf16(qf[0], bb[i & 1][0], acc, 0, 0, 0);
    acc = __builtin_amdgcn_mfma_f32_16x16x32_bf16(qf[1], bb[i & 1][1], acc, 0, 0, 0);
    acc = __builtin_amdgcn_mfma_f32_16x16x32_bf16(qf[2], bb[i & 1][2], acc, 0, 0, 0);
    acc = __builtin_amdgcn_mfma_f32_16x16x32_bf16(qf[3], bb[i & 1][3], acc, 0, 0, 0);
    const int tl = (wq + 8 * (i >> 2)) * 64 + (i & 3) * 16 + colL;
    const int widx = tl >> 5, wb = tl & 31;
#pragma unroll
    for (int r = 0; r < 4; ++r) {
      int row_l = rbase + r;
      unsigned mw = mk[row_l * 65 + widx];
      float e = ((mw >> wb) & 1u) ? 0.f : __expf(fminf(acc[r], 80.f));
      z[r] += e;
      pt[row_l * 2048 + (tl ^ ((row_l & 7) << 3))] = f2bf(e);
    }
  }

  // Z: reduce each lane's partial over the 16 t-lanes, then cross-wave
#pragma unroll
  for (int r = 0; r < 4; ++r) {
    float s = z[r];
    s += __shfl_xor(s, 1, 64);
    s += __shfl_xor(s, 2, 64);
    s += __shfl_xor(s, 4, 64);
    s += __shfl_xor(s, 8, 64);
    if (colL == 0) atomicAdd(&zfin[rbase + r], s);
  }
  __syncthreads();   // pt complete (all waves) + zfin complete   [barrier 2]
  if (tid < 16) zinvl[tid] = 1.0f / fmaxf(zfin[tid], 1e-30f);
  __syncthreads();   //                                            [barrier 3]

  // column sums from pt
  {
    const int t0 = tid * 4;
    float a0 = 0.f, a1 = 0.f, a2 = 0.f, a3 = 0.f;
#pragma unroll
    for (int r = 0; r < 16; ++r) {
      const unsigned short* pr = pt + r * 2048 + (t0 ^ ((r & 7) << 3));
      ushort4 pv = *(const ushort4*)pr;
      float zi = zinvl[r];
      a0 += bf2f(pv.x) * zi;
      a1 += bf2f(pv.y) * zi;
      a2 += bf2f(pv.z) * zi;
      a3 += bf2f(pv.w) * zi;
    }
    float4 o4;
    o4.x = a0; o4.y = a1; o4.z = a2; o4.w = a3;
    *(float4*)(wgp + ((size_t)b * 128 + blockIdx.x) * SS + t0) = o4;
  }
}

// ---------------- tail: wgp-reduce (128 partials), y = w.V, out = (y/S)@Wl + bl ---------
__global__ __launch_bounds__(1024) void k_tail(const float* __restrict__ wgp,
                                               const unsigned short* __restrict__ vg,
                                               const float* __restrict__ Wl,
                                               const float* __restrict__ bl,
                                               float* __restrict__ outp) {
  __shared__ float ws2[2048];
  __shared__ float yp[8][128];
  __shared__ float ys[128];
  const int tid = threadIdx.x;
  const int b = blockIdx.x;

  {
    float s0 = 0.f, s1 = 0.f;
    const float* wp = wgp + ((size_t)b * 128) * SS + tid * 2;
#pragma unroll 8
    for (int rg = 0; rg < 128; ++rg) {
      s0 += wp[(size_t)rg * SS];
      s1 += wp[(size_t)rg * SS + 1];
    }
    ws2[tid * 2] = s0;
    ws2[tid * 2 + 1] = s1;
  }
  __syncthreads();

  {
    const int d = tid & 127, tg = tid >> 7;
    const int t0 = tg * 256;
    float p = 0.f;
    const unsigned short* vr = vg + ((size_t)b * SS + t0) * DD + d;
#pragma unroll 8
    for (int t = 0; t < 256; ++t) p += ws2[t0 + t] * bf2f(vr[(size_t)t * DD]);
    yp[tg][d] = p;
  }
  __syncthreads();
  if (tid < 128) {
    float a = 0.f;
#pragma unroll
    for (int g = 0; g < 8; ++g) a += yp[g][tid];
    ys[tid] = a * (1.0f / 2048.0f);
  }
  __syncthreads();

  if (tid < CC) {
    float a = bl[tid];
#pragma unroll 16
    for (int dd = 0; dd < DD; ++dd) a += ys[dd] * Wl[dd * CC + tid];
    outp[b * CC + tid] = a;
  }
}

extern "C" void kernel_launch(void* const* d_in, const int* in_sizes, int n_in,
                              void* d_out, int out_size, void* d_ws, size_t ws_size,
                              hipStream_t stream) {
  const void* ptr[10];
  for (int i = 0; i < 10; ++i) ptr[i] = (i < n_in) ? d_in[i] : nullptr;
  if (n_in == 10) {  // size-based slot matching (no-op under dict order)
    const void *px = 0, *pm = 0, *pWl = 0, *pbl = 0;
    const void* pW[3] = {0, 0, 0};
    const void* pb[3] = {0, 0, 0};
    int nW = 0, nb = 0;
    for (int i = 0; i < 10; ++i) {
      int s = in_sizes[i];
      if (s == 16777216) px = d_in[i];
      else if (s == 67108864) pm = d_in[i];
      else if (s == 128000) pWl = d_in[i];
      else if (s == 1000) pbl = d_in[i];
      else if (s == 65536 && nW < 3) pW[nW++] = d_in[i];
      else if (s == 128 && nb < 3) pb[nb++] = d_in[i];
    }
    if (px && pm && pWl && pbl && nW == 3 && nb == 3) {
      ptr[0] = px; ptr[1] = pm;
      ptr[2] = pW[0]; ptr[3] = pb[0];
      ptr[4] = pW[1]; ptr[5] = pb[1];
      ptr[6] = pW[2]; ptr[7] = pb[2];
      ptr[8] = pWl; ptr[9] = pbl;
    }
  }
  char* ws = (char*)d_ws;
  if (ws_size < (size_t)WS_END) return;
  unsigned* pk = (unsigned*)(ws + WS_PK);
  unsigned short* q  = (unsigned short*)(ws + WS_Q);
  unsigned short* k  = (unsigned short*)(ws + WS_K);
  unsigned short* v  = (unsigned short*)(ws + WS_V);
  unsigned short* wt = (unsigned short*)(ws + WS_WT);
  float* wgp = (float*)(ws + WS_WGP);

  k_prep<<<2048, 256, 0, stream>>>(ptr[1], (const float*)ptr[2], (const float*)ptr[4],
                                   (const float*)ptr[6], wt, pk);
  k_proj<<<dim3(256, 3), 256, 0, stream>>>((const float*)ptr[0], wt,
                                           (const float*)ptr[3], (const float*)ptr[5],
                                           (const float*)ptr[7], q, k, v);
  k_fatt<<<dim3(128, 16), 512, 0, stream>>>(q, k, pk, wgp);
  k_tail<<<16, 1024, 0, stream>>>(wgp, v, (const float*)ptr[8], (const float*)ptr[9],
                                  (float*)d_out);
}

// Round 11
// 577.605 us; speedup vs baseline: 1.0896x; 1.0896x over previous
//
#include <hip/hip_runtime.h>
#include <stdint.h>

#define BB 16
#define SS 2048
#define FF 512
#define DD 128
#define CC 1000

typedef __attribute__((ext_vector_type(8))) short bf16x8;
typedef __attribute__((ext_vector_type(4))) float f32x4;

__device__ __forceinline__ unsigned short f2bf(float f) {
  unsigned x;
  __builtin_memcpy(&x, &f, 4);
  x = x + 0x7FFFu + ((x >> 16) & 1u);
  return (unsigned short)(x >> 16);
}
__device__ __forceinline__ float bf2f(unsigned short u) {
  unsigned x = ((unsigned)u) << 16;
  float f;
  __builtin_memcpy(&f, &x, 4);
  return f;
}
__device__ __forceinline__ unsigned pk2(float a, float b) {
  return (unsigned)f2bf(a) | ((unsigned)f2bf(b) << 16);
}

// ---- workspace layout (bytes) ----
#define WS_PK   0          // packed mask bits uint32 [B][S][64] (8 MB)
#define WS_Q    8388608    // bf16 [B][S][128], q pre-scaled by D^-0.5
#define WS_K    16777216
#define WS_V    25165824
#define WS_WT   33554432   // bf16 WT[3][128][512]
#define WS_WGP  33947648   // float wgp[B][64 rowgroups][2048] partial colsums (8 MB)
#define WS_END  42336256

// ---------------- prep: mask probe (per-block) + mask pack + W transpose ----------------
__global__ __launch_bounds__(256) void k_prep(const void* __restrict__ mask,
                                              const float* __restrict__ Wq,
                                              const float* __restrict__ Wk,
                                              const float* __restrict__ Wv,
                                              unsigned short* __restrict__ wt,
                                              unsigned* __restrict__ pk) {
  __shared__ unsigned red;
  const int tid = threadIdx.x;
  if (tid == 0) red = 0;
  __syncthreads();
  {  // probe the global mask head (4 KB): int32 masks never set bits 8..31
    unsigned a = 0;
    const unsigned* m32 = (const unsigned*)mask;
#pragma unroll
    for (int j = 0; j < 4; ++j) a |= m32[tid * 4 + j] & 0xFFFFFF00u;
    if (a) atomicOr(&red, 1u);
  }
  __syncthreads();
  const bool isInt = (red == 0);

  const long long base = (long long)blockIdx.x * 32768;
  for (int it = 0; it < 128; ++it) {
    long long e = base + it * 256 + tid;
    int val;
    if (isInt) val = ((const int*)mask)[e];
    else       val = ((const unsigned char*)mask)[e];
    unsigned long long bal = __ballot(val != 0);
    if ((tid & 31) == 0)
      pk[e >> 5] = (unsigned)((tid & 63) ? (bal >> 32) : bal);
  }

  if (blockIdx.x < 768) {
    int idx = blockIdx.x * 256 + tid;
    int ty = idx >> 16;
    int o = idx & 65535;
    int d = o >> 9, f = o & 511;
    const float* W = ty == 0 ? Wq : (ty == 1 ? Wk : Wv);
    wt[idx] = f2bf(W[f * DD + d]);
  }
}

// ---------------- QKV projection (R4-proven, verbatim) ----------------
__global__ __launch_bounds__(256) void k_proj(const float* __restrict__ xg,
                                              const unsigned short* __restrict__ wtg,
                                              const float* __restrict__ bq,
                                              const float* __restrict__ bk,
                                              const float* __restrict__ bv,
                                              unsigned short* __restrict__ qo,
                                              unsigned short* __restrict__ ko,
                                              unsigned short* __restrict__ vo) {
  __shared__ __align__(16) char lA[8192];
  __shared__ __align__(16) char lB[8192];
  const int tid = threadIdx.x;
  const int lane = tid & 63;
  const int wv = tid >> 6;
  const int colL = lane & 15, quad = lane >> 4;
  const int blk = blockIdx.x, ty = blockIdx.y;
  const float* bias = ty == 0 ? bq : (ty == 1 ? bk : bv);
  unsigned short* outp = ty == 0 ? qo : (ty == 1 ? ko : vo);
  const float scale = ty == 0 ? 0.08838834764831845f : 1.0f;
  const unsigned short* wbase = wtg + (size_t)ty * 65536;
  const int m0 = (wv & 1) * 64, n0 = (wv >> 1) * 64;

  f32x4 acc[4][4];
  const f32x4 z4 = {0.f, 0.f, 0.f, 0.f};
#pragma unroll
  for (int mi = 0; mi < 4; ++mi)
#pragma unroll
    for (int ni = 0; ni < 4; ++ni) acc[mi][ni] = z4;

  for (int ic = 0; ic < 16; ++ic) {
    const int k0 = ic * 32;
    uint4 va[2], vb[2];
#pragma unroll
    for (int rr = 0; rr < 2; ++rr) {
      int p = rr * 256 + tid;
      int row = p >> 2, c = p & 3;
      const float* xp = xg + (size_t)(blk * 128 + row) * FF + k0 + c * 8;
      float4 x0 = *(const float4*)xp;
      float4 x1 = *(const float4*)(xp + 4);
      va[rr].x = pk2(x0.x, x0.y); va[rr].y = pk2(x0.z, x0.w);
      va[rr].z = pk2(x1.x, x1.y); va[rr].w = pk2(x1.z, x1.w);
      vb[rr] = *(const uint4*)(wbase + (size_t)row * FF + k0 + c * 8);
    }
    __syncthreads();
#pragma unroll
    for (int rr = 0; rr < 2; ++rr) {
      int p = rr * 256 + tid;
      int row = p >> 2, c = p & 3;
      int phys = c ^ ((row >> 1) & 3);
      *(uint4*)(lA + row * 64 + phys * 16) = va[rr];
      *(uint4*)(lB + row * 64 + phys * 16) = vb[rr];
    }
    __syncthreads();
    bf16x8 af[4], bfr[4];
#pragma unroll
    for (int mi = 0; mi < 4; ++mi) {
      int ar = m0 + mi * 16 + colL;
      int phys = quad ^ ((ar >> 1) & 3);
      af[mi] = *(const bf16x8*)(lA + ar * 64 + phys * 16);
    }
#pragma unroll
    for (int ni = 0; ni < 4; ++ni) {
      int br = n0 + ni * 16 + colL;
      int phys = quad ^ ((br >> 1) & 3);
      bfr[ni] = *(const bf16x8*)(lB + br * 64 + phys * 16);
    }
#pragma unroll
    for (int mi = 0; mi < 4; ++mi)
#pragma unroll
      for (int ni = 0; ni < 4; ++ni)
        acc[mi][ni] = __builtin_amdgcn_mfma_f32_16x16x32_bf16(af[mi], bfr[ni], acc[mi][ni], 0, 0, 0);
  }
#pragma unroll
  for (int ni = 0; ni < 4; ++ni) {
    int col = n0 + ni * 16 + colL;
    float bval = bias[col];
#pragma unroll
    for (int mi = 0; mi < 4; ++mi) {
#pragma unroll
      for (int r = 0; r < 4; ++r) {
        int row = blk * 128 + m0 + mi * 16 + quad * 4 + r;
        float val = (acc[mi][ni][r] + bval) * scale;
        outp[(size_t)row * DD + col] = f2bf(val);
      }
    }
  }
}

// ---------------- fused attention: P kept entirely in LDS (R4-proven, verbatim) ----------
// Block = (32 q-rows, batch b), 512 thr = 8 waves (wr row-half, wq t-quarter).
// Sweeps all 2048 t in 32 chunks of 64 (K staged in LDS, reg-prefetched).
// P tile 32x2048 bf16 = 128 KB LDS (row-XOR swizzle). Z block-local; after
// the sweep: zinv, column sums -> per-rowgroup wgp partials (plain stores).
__global__ __launch_bounds__(512, 2) void k_fatt(const unsigned short* __restrict__ qg,
                                                 const unsigned short* __restrict__ kg,
                                                 const unsigned* __restrict__ pk,
                                                 float* __restrict__ wgp) {
  extern __shared__ __align__(16) char smem[];
  unsigned short* pt = (unsigned short*)smem;          // [32][2048] bf16, 131072 B
  char* kt = smem + 131072;                            // [64][256 B] swizzled, 16384 B
  unsigned* mk = (unsigned*)(smem + 147456);           // [32][65] mask words, 8320 B
  float* zfin = (float*)(smem + 155776);               // [32]
  float* zinvl = (float*)(smem + 155904);              // [32]

  const int tid = threadIdx.x;
  const int lane = tid & 63, wv = tid >> 6;
  const int colL = lane & 15, quad = lane >> 4;
  const int wr = wv & 1, wq = wv >> 1;
  const int r0 = blockIdx.x * 32;
  const int b = blockIdx.y;

  for (int i = tid; i < 2048; i += 512) {
    int row = i >> 6, w = i & 63;
    mk[row * 65 + w] = pk[((size_t)b * SS + r0 + row) * 64 + w];
  }
  if (tid < 32) zfin[tid] = 0.f;

  bf16x8 qf[4];
  {
    int qrow = r0 + wr * 16 + colL;
    const unsigned short* qp = qg + ((size_t)b * SS + qrow) * DD + quad * 8;
#pragma unroll
    for (int kk = 0; kk < 4; ++kk) qf[kk] = *(const bf16x8*)(qp + kk * 32);
  }

  const int krow = tid >> 3, kc8 = tid & 7;
  const unsigned short* kbase = kg + ((size_t)b * SS + krow) * DD;
  const int kswz0 = (kc8 ^ (krow & 7)) * 16;
  const int kswz1 = ((kc8 + 8) ^ (krow & 7)) * 16;

  uint4 kreg0 = *(const uint4*)(kbase + kc8 * 8);
  uint4 kreg1 = *(const uint4*)(kbase + kc8 * 8 + 64);
  *(uint4*)(kt + krow * 256 + kswz0) = kreg0;
  *(uint4*)(kt + krow * 256 + kswz1) = kreg1;
  __syncthreads();

  float z[4] = {0.f, 0.f, 0.f, 0.f};
  const int tb = wq * 16 + colL;

  for (int c = 0; c < 32; ++c) {
    if (c < 31) {
      const unsigned short* kb2 = kbase + (size_t)(c + 1) * 64 * DD;
      kreg0 = *(const uint4*)(kb2 + kc8 * 8);
      kreg1 = *(const uint4*)(kb2 + kc8 * 8 + 64);
    }
    bf16x8 bb[4];
#pragma unroll
    for (int kk = 0; kk < 4; ++kk) {
      int phys = (kk * 4 + quad) ^ (tb & 7);
      bb[kk] = *(const bf16x8*)(kt + tb * 256 + phys * 16);
    }
    f32x4 acc = {0.f, 0.f, 0.f, 0.f};
    acc = __builtin_amdgcn_mfma_f32_16x16x32_bf16(qf[0], bb[0], acc, 0, 0, 0);
    acc = __builtin_amdgcn_mfma_f32_16x16x32_bf16(qf[1], bb[1], acc, 0, 0, 0);
    acc = __builtin_amdgcn_mfma_f32_16x16x32_bf16(qf[2], bb[2], acc, 0, 0, 0);
    acc = __builtin_amdgcn_mfma_f32_16x16x32_bf16(qf[3], bb[3], acc, 0, 0, 0);
    int tl = c * 64 + tb;
    int widx = tl >> 5, wb = tl & 31;
#pragma unroll
    for (int r = 0; r < 4; ++r) {
      int row_l = wr * 16 + quad * 4 + r;
      unsigned mw = mk[row_l * 65 + widx];
      float e = ((mw >> wb) & 1u) ? 0.f : __expf(fminf(acc[r], 80.f));
      z[r] += e;
      pt[row_l * 2048 + (tl ^ ((row_l & 7) << 3))] = f2bf(e);
    }
    if (c < 31) {
      __syncthreads();
      *(uint4*)(kt + krow * 256 + kswz0) = kreg0;
      *(uint4*)(kt + krow * 256 + kswz1) = kreg1;
      __syncthreads();
    }
  }

#pragma unroll
  for (int r = 0; r < 4; ++r) {
    float s = z[r];
    s += __shfl_xor(s, 1, 64);
    s += __shfl_xor(s, 2, 64);
    s += __shfl_xor(s, 4, 64);
    s += __shfl_xor(s, 8, 64);
    if (colL == 0) atomicAdd(&zfin[wr * 16 + quad * 4 + r], s);
  }
  __syncthreads();
  if (tid < 32) zinvl[tid] = 1.0f / fmaxf(zfin[tid], 1e-30f);
  __syncthreads();

  {
    const int t0 = tid * 4;
    float a0 = 0.f, a1 = 0.f, a2 = 0.f, a3 = 0.f;
#pragma unroll 8
    for (int r = 0; r < 32; ++r) {
      const unsigned short* pr = pt + r * 2048 + (t0 ^ ((r & 7) << 3));
      ushort4 pv = *(const ushort4*)pr;
      float zi = zinvl[r];
      a0 += bf2f(pv.x) * zi;
      a1 += bf2f(pv.y) * zi;
      a2 += bf2f(pv.z) * zi;
      a3 += bf2f(pv.w) * zi;
    }
    float4 o4;
    o4.x = a0; o4.y = a1; o4.z = a2; o4.w = a3;
    *(float4*)(wgp + ((size_t)b * 64 + blockIdx.x) * SS + t0) = o4;
  }
}

// ---------------- tail: wgp-reduce, y = w.V, out = (y/S)@Wl + bl (R4-proven) -------------
__global__ __launch_bounds__(1024) void k_tail(const float* __restrict__ wgp,
                                               const unsigned short* __restrict__ vg,
                                               const float* __restrict__ Wl,
                                               const float* __restrict__ bl,
                                               float* __restrict__ outp) {
  __shared__ float ws2[2048];
  __shared__ float yp[8][128];
  __shared__ float ys[128];
  const int tid = threadIdx.x;
  const int b = blockIdx.x;

  {
    float s0 = 0.f, s1 = 0.f;
    const float* wp = wgp + ((size_t)b * 64) * SS + tid * 2;
#pragma unroll 8
    for (int rg = 0; rg < 64; ++rg) {
      s0 += wp[rg * SS];
      s1 += wp[rg * SS + 1];
    }
    ws2[tid * 2] = s0;
    ws2[tid * 2 + 1] = s1;
  }
  __syncthreads();

  {
    const int d = tid & 127, tg = tid >> 7;
    const int t0 = tg * 256;
    float p = 0.f;
    const unsigned short* vr = vg + ((size_t)b * SS + t0) * DD + d;
#pragma unroll 8
    for (int t = 0; t < 256; ++t) p += ws2[t0 + t] * bf2f(vr[(size_t)t * DD]);
    yp[tg][d] = p;
  }
  __syncthreads();
  if (tid < 128) {
    float a = 0.f;
#pragma unroll
    for (int g = 0; g < 8; ++g) a += yp[g][tid];
    ys[tid] = a * (1.0f / 2048.0f);
  }
  __syncthreads();

  if (tid < CC) {
    float a = bl[tid];
#pragma unroll 16
    for (int dd = 0; dd < DD; ++dd) a += ys[dd] * Wl[dd * CC + tid];
    outp[b * CC + tid] = a;
  }
}

extern "C" void kernel_launch(void* const* d_in, const int* in_sizes, int n_in,
                              void* d_out, int out_size, void* d_ws, size_t ws_size,
                              hipStream_t stream) {
  const void* ptr[10];
  for (int i = 0; i < 10; ++i) ptr[i] = (i < n_in) ? d_in[i] : nullptr;
  if (n_in == 10) {  // size-based slot matching (no-op under dict order)
    const void *px = 0, *pm = 0, *pWl = 0, *pbl = 0;
    const void* pW[3] = {0, 0, 0};
    const void* pb[3] = {0, 0, 0};
    int nW = 0, nb = 0;
    for (int i = 0; i < 10; ++i) {
      int s = in_sizes[i];
      if (s == 16777216) px = d_in[i];
      else if (s == 67108864) pm = d_in[i];
      else if (s == 128000) pWl = d_in[i];
      else if (s == 1000) pbl = d_in[i];
      else if (s == 65536 && nW < 3) pW[nW++] = d_in[i];
      else if (s == 128 && nb < 3) pb[nb++] = d_in[i];
    }
    if (px && pm && pWl && pbl && nW == 3 && nb == 3) {
      ptr[0] = px; ptr[1] = pm;
      ptr[2] = pW[0]; ptr[3] = pb[0];
      ptr[4] = pW[1]; ptr[5] = pb[1];
      ptr[6] = pW[2]; ptr[7] = pb[2];
      ptr[8] = pWl; ptr[9] = pbl;
    }
  }
  char* ws = (char*)d_ws;
  if (ws_size < (size_t)WS_END) return;
  unsigned* pk = (unsigned*)(ws + WS_PK);
  unsigned short* q  = (unsigned short*)(ws + WS_Q);
  unsigned short* k  = (unsigned short*)(ws + WS_K);
  unsigned short* v  = (unsigned short*)(ws + WS_V);
  unsigned short* wt = (unsigned short*)(ws + WS_WT);
  float* wgp = (float*)(ws + WS_WGP);

  k_prep<<<2048, 256, 0, stream>>>(ptr[1], (const float*)ptr[2], (const float*)ptr[4],
                                   (const float*)ptr[6], wt, pk);
  k_proj<<<dim3(256, 3), 256, 0, stream>>>((const float*)ptr[0], wt,
                                           (const float*)ptr[3], (const float*)ptr[5],
                                           (const float*)ptr[7], q, k, v);
  k_fatt<<<dim3(64, 16), 512, 156032, stream>>>(q, k, pk, wgp);
  k_tail<<<16, 1024, 0, stream>>>(wgp, v, (const float*)ptr[8], (const float*)ptr[9],
                                  (float*)d_out);
}